// Round 6
// baseline (201.275 us; speedup 1.0000x reference)
//
#include <hip/hip_runtime.h>

// UpsampleUpFIRDn (up=2, 4x4 FIR). Wave-per-4-input-rows: lane t holds float4
// of input cols 4t..4t+3 for rows R-1..R+4 (6 loads, all independent);
// produces output rows 2R..2R+7, cols 8t..8t+7. Halos via __shfl.
// Stores: plain L2-cached (nontemporal caused 2.4x write amplification),
// widest aligned vectors per wave-uniform row alignment.
//
// Weight map: oy even -> row weights k[3][*] (top tap), k[1][*] (bottom);
//             oy odd  -> k[2][*], k[0][*]; cols likewise by ox parity.

typedef float v2f __attribute__((ext_vector_type(2)));
typedef float v4f __attribute__((ext_vector_type(4)));

__device__ __forceinline__ void store8(float* b, const float v[8], int r, int tail)
{
    // b = row segment base, r = (float index of b) & 3 (wave-uniform).
    // tail: lane 63 — only v[0..6] valid (ox=504..510).
    if (r == 0) {
        *(v4f*)b = (v4f){v[0], v[1], v[2], v[3]};
        if (!tail) *(v4f*)(b + 4) = (v4f){v[4], v[5], v[6], v[7]};
        else { *(v2f*)(b + 4) = (v2f){v[4], v[5]}; b[6] = v[6]; }
    } else if (r == 1) {
        b[0] = v[0];
        *(v2f*)(b + 1) = (v2f){v[1], v[2]};
        *(v4f*)(b + 3) = (v4f){v[3], v[4], v[5], v[6]};
        if (!tail) b[7] = v[7];
    } else if (r == 2) {
        *(v2f*)b = (v2f){v[0], v[1]};
        *(v4f*)(b + 2) = (v4f){v[2], v[3], v[4], v[5]};
        if (!tail) *(v2f*)(b + 6) = (v2f){v[6], v[7]};
        else b[6] = v[6];
    } else {
        b[0] = v[0];
        *(v4f*)(b + 1) = (v4f){v[1], v[2], v[3], v[4]};
        *(v2f*)(b + 5) = (v2f){v[5], v[6]};
        if (!tail) b[7] = v[7];
    }
}

__global__ __launch_bounds__(256) void up2_k4_wave4(
    const float* __restrict__ x, const float* __restrict__ kw,
    float* __restrict__ out)
{
    const int H = 256, W = 256, OH = 511, OW = 511;
    int t  = threadIdx.x;                        // lane 0..63
    int wv = threadIdx.y;                        // wave 0..3
    int R  = blockIdx.y * 16 + wv * 4;           // first input row of this wave
    int bc = blockIdx.z;

    const float4* k4 = (const float4*)kw;        // uniform -> SGPR loads
    float4 K0 = k4[0], K1 = k4[1], K2 = k4[2], K3 = k4[3];

    const float* xp = x + (size_t)bc * (H * W);

    // 6 independent row loads (rows R-1 .. R+4, clamped)
    float4 A[6];
    #pragma unroll
    for (int i = 0; i < 6; ++i) {
        int rr = R - 1 + i;
        rr = rr < 0 ? 0 : (rr > H - 1 ? H - 1 : rr);
        A[i] = ((const float4*)(xp + (size_t)rr * W))[t];
    }
    if (R == 0) { A[0].x = A[0].y = A[0].z = A[0].w = 0.f; }  // pad row above

    // halos: left = prev lane's .w, right = next lane's .x
    float Lh[6], Rh[6];
    #pragma unroll
    for (int i = 0; i < 6; ++i) {
        Lh[i] = __shfl_up(A[i].w, 1);
        Rh[i] = __shfl_down(A[i].x, 1);   // lane 63: garbage, feeds unstored e[7]/o[7]
        if (t == 0) Lh[i] = 0.f;
    }

    size_t plane = (size_t)bc * OH * OW;
    int tail = (t == 63);

    #pragma unroll
    for (int j = 0; j < 4; ++j) {
        int ty = R + j;
        float4 m = A[j], z = A[j + 1], p = A[j + 2];
        float mL = Lh[j], zL = Lh[j + 1], pL = Lh[j + 2];
        float mR = Rh[j], zR = Rh[j + 1], pR = Rh[j + 2];

        float e[8], o[8];
        // even out-row (2ty): rows (ty-1 -> K3, ty -> K1)
        e[0] = K3.w*mL  + K3.y*m.x + K1.w*zL  + K1.y*z.x;
        e[1] = K3.z*m.x + K3.x*m.y + K1.z*z.x + K1.x*z.y;
        e[2] = K3.w*m.x + K3.y*m.y + K1.w*z.x + K1.y*z.y;
        e[3] = K3.z*m.y + K3.x*m.z + K1.z*z.y + K1.x*z.z;
        e[4] = K3.w*m.y + K3.y*m.z + K1.w*z.y + K1.y*z.z;
        e[5] = K3.z*m.z + K3.x*m.w + K1.z*z.z + K1.x*z.w;
        e[6] = K3.w*m.z + K3.y*m.w + K1.w*z.z + K1.y*z.w;
        e[7] = K3.z*m.w + K3.x*mR  + K1.z*z.w + K1.x*zR;
        // odd out-row (2ty+1): rows (ty -> K2, ty+1 -> K0)
        o[0] = K2.w*zL  + K2.y*z.x + K0.w*pL  + K0.y*p.x;
        o[1] = K2.z*z.x + K2.x*z.y + K0.z*p.x + K0.x*p.y;
        o[2] = K2.w*z.x + K2.y*z.y + K0.w*p.x + K0.y*p.y;
        o[3] = K2.z*z.y + K2.x*z.z + K0.z*p.y + K0.x*p.z;
        o[4] = K2.w*z.y + K2.y*z.z + K0.w*p.y + K0.y*p.z;
        o[5] = K2.z*z.z + K2.x*z.w + K0.z*p.z + K0.x*p.w;
        o[6] = K2.w*z.z + K2.y*z.w + K0.w*p.z + K0.y*p.w;
        o[7] = K2.z*z.w + K2.x*zR  + K0.z*p.w + K0.x*pR;

        size_t erow = plane + (size_t)(2 * ty) * OW;
        int ra = (int)(erow & 3);
        store8(out + erow + 8 * t, e, ra, tail);
        if (ty < H - 1) {
            store8(out + erow + OW + 8 * t, o, (ra + 3) & 3, tail);  // OW odd: parity +3
        }
    }
}

extern "C" void kernel_launch(void* const* d_in, const int* in_sizes, int n_in,
                              void* d_out, int out_size, void* d_ws, size_t ws_size,
                              hipStream_t stream) {
    const float* x = (const float*)d_in[0];
    const float* k = (const float*)d_in[1];
    float* out = (float*)d_out;

    const int H = 256, W = 256;
    int BC = in_sizes[0] / (H * W);   // 512

    dim3 block(64, 4, 1);             // 4 waves, each owns 4 input rows
    dim3 grid(1, H / 16, BC);         // (1, 16, 512)
    hipLaunchKernelGGL(up2_k4_wave4, grid, block, 0, stream, x, k, out);
}

// Round 7
// 126.830 us; speedup vs baseline: 1.5870x; 1.5870x over previous
//
#include <hip/hip_runtime.h>

// UpsampleUpFIRDn (up=2, 4x4 FIR). Wave-per-input-row; outputs staged through
// LDS so ALL global stores are dense, 16B-aligned dwordx4 (hypothesis: cached
// misaligned vector stores caused ~2x DRAM write amplification; dense scalar
// stores in round 0 measured WRITE_SIZE == output bytes exactly).
//
// Per wave: lane t loads float4 of input cols 4t..4t+3 for rows ty-1,ty,ty+1;
// computes output rows 2ty (e[8]) and 2ty+1 (o[8]) for cols 8t..8t+7; stages
// the 1022-float contiguous row-pair into a swizzled LDS buffer; then lanes
// cooperatively store the flat region [P, P+1022) as aligned vec4s.
//
// Weight map: oy even -> row weights k[3][*] (top tap), k[1][*] (bottom);
//             oy odd  -> k[2][*], k[0][*]; cols likewise by ox parity.

typedef float v4f __attribute__((ext_vector_type(4)));

__device__ __forceinline__ int SW(int i) {        // XOR swizzle, bijective in [0,1024)
    return i ^ (((i >> 5) & 7) << 2);
}

__global__ __launch_bounds__(256) void up2_k4_ldsT(
    const float* __restrict__ x, const float* __restrict__ kw,
    float* __restrict__ out)
{
    const int H = 256, W = 256, OW = 511;
    __shared__ float lds[4][1024];

    int t  = threadIdx.x;                     // lane 0..63
    int wv = threadIdx.y;                     // wave 0..3
    int ty = blockIdx.y * 4 + wv;             // input row 0..255
    int bc = blockIdx.z;
    float* buf = lds[wv];

    const float4* k4 = (const float4*)kw;     // uniform -> SGPR loads
    float4 K0 = k4[0], K1 = k4[1], K2 = k4[2], K3 = k4[3];

    const float* xp = x + (size_t)bc * (H * W);
    int rm = (ty > 0) ? ty - 1 : 0;
    int rp = (ty < H - 1) ? ty + 1 : H - 1;
    float4 m = ((const float4*)(xp + (size_t)rm * W))[t];
    float4 z = ((const float4*)(xp + (size_t)ty * W))[t];
    float4 p = ((const float4*)(xp + (size_t)rp * W))[t];
    if (ty == 0) { m.x = m.y = m.z = m.w = 0.f; }

    float mL = __shfl_up(m.w, 1), zL = __shfl_up(z.w, 1), pL = __shfl_up(p.w, 1);
    float mR = __shfl_down(m.x, 1), zR = __shfl_down(z.x, 1), pR = __shfl_down(p.x, 1);
    if (t == 0) { mL = 0.f; zL = 0.f; pL = 0.f; }
    // lane 63: mR/zR/pR garbage -> e[7]/o[7] garbage; e[7] slot gets
    // overwritten by o[0] (later instruction wins), o[7] slot (1022) unstored.

    float e[8], o[8];
    // even out-row (2ty): rows (ty-1 -> K3, ty -> K1)
    e[0] = K3.w*mL  + K3.y*m.x + K1.w*zL  + K1.y*z.x;
    e[1] = K3.z*m.x + K3.x*m.y + K1.z*z.x + K1.x*z.y;
    e[2] = K3.w*m.x + K3.y*m.y + K1.w*z.x + K1.y*z.y;
    e[3] = K3.z*m.y + K3.x*m.z + K1.z*z.y + K1.x*z.z;
    e[4] = K3.w*m.y + K3.y*m.z + K1.w*z.y + K1.y*z.z;
    e[5] = K3.z*m.z + K3.x*m.w + K1.z*z.z + K1.x*z.w;
    e[6] = K3.w*m.z + K3.y*m.w + K1.w*z.z + K1.y*z.w;
    e[7] = K3.z*m.w + K3.x*mR  + K1.z*z.w + K1.x*zR;
    // odd out-row (2ty+1): rows (ty -> K2, ty+1 -> K0)
    o[0] = K2.w*zL  + K2.y*z.x + K0.w*pL  + K0.y*p.x;
    o[1] = K2.z*z.x + K2.x*z.y + K0.z*p.x + K0.x*p.y;
    o[2] = K2.w*z.x + K2.y*z.y + K0.w*p.x + K0.y*p.y;
    o[3] = K2.z*z.y + K2.x*z.z + K0.z*p.y + K0.x*p.z;
    o[4] = K2.w*z.y + K2.y*z.z + K0.w*p.y + K0.y*p.z;
    o[5] = K2.z*z.z + K2.x*z.w + K0.z*p.z + K0.x*p.w;
    o[6] = K2.w*z.z + K2.y*z.w + K0.w*p.z + K0.y*p.w;
    o[7] = K2.z*z.w + K2.x*zR  + K0.z*p.w + K0.x*pR;

    // stage row-pair into LDS: region float r lives at buf[SW(r)].
    // e -> region [8t .. 8t+7], o -> region [511+8t .. 511+8t+7]
    #pragma unroll
    for (int j = 0; j < 8; ++j) buf[SW(8 * t + j)] = e[j];
    #pragma unroll
    for (int j = 0; j < 8; ++j) buf[SW(511 + 8 * t + j)] = o[j];

    __syncthreads();

    size_t plane = (size_t)bc * (511 * 511);
    size_t P = plane + (size_t)(2 * ty) * OW;      // region base (float idx)
    int h = (int)((4 - (P & 3)) & 3);              // head scalars to align to 16B
    int nvalid = (ty < H - 1) ? 1022 : 511;        // ty=255: only even row exists

    if (t < h) out[P + t] = buf[SW(t)];

    #pragma unroll
    for (int q = 0; q < 4; ++q) {
        int base = h + 256 * q + 4 * t;
        float v0 = buf[SW(min(base,     1023))];
        float v1 = buf[SW(min(base + 1, 1023))];
        float v2 = buf[SW(min(base + 2, 1023))];
        float v3 = buf[SW(min(base + 3, 1023))];
        if (base + 3 < nvalid) {
            *(v4f*)(out + P + base) = (v4f){v0, v1, v2, v3};
        } else {
            if (base     < nvalid) out[P + base]     = v0;
            if (base + 1 < nvalid) out[P + base + 1] = v1;
            if (base + 2 < nvalid) out[P + base + 2] = v2;
        }
    }
}

extern "C" void kernel_launch(void* const* d_in, const int* in_sizes, int n_in,
                              void* d_out, int out_size, void* d_ws, size_t ws_size,
                              hipStream_t stream) {
    const float* x = (const float*)d_in[0];
    const float* k = (const float*)d_in[1];
    float* out = (float*)d_out;

    const int H = 256, W = 256;
    int BC = in_sizes[0] / (H * W);   // 512

    dim3 block(64, 4, 1);             // 4 waves; each owns one input row
    dim3 grid(1, H / 4, BC);          // (1, 64, 512)
    hipLaunchKernelGGL(up2_k4_ldsT, grid, block, 0, stream, x, k, out);
}